// Round 2
// baseline (161.129 us; speedup 1.0000x reference)
//
#include <hip/hip_runtime.h>

#define D_DIM 8192
#define BK 128
#define SPLITK 8
#define KS (D_DIM / SPLITK)      // 1024 per slice
#define NCHUNK (KS / BK)         // 8
#define BN 32

typedef float f32x4 __attribute__((ext_vector_type(4)));
typedef short s16x8 __attribute__((ext_vector_type(8)));
typedef short s16x4 __attribute__((ext_vector_type(4)));

__device__ __forceinline__ unsigned short f2bf(float f) {
  union { float f; unsigned u; } v; v.f = f;
  return (unsigned short)((v.u + 0x7FFFu + ((v.u >> 16) & 1u)) >> 16);
}

// Stage one BK-chunk of x (32 batches) and W (32 rows) into registers.
// Flat float4 index f = tid + t*256: row = f>>5, col4 = f&31 (BK/4 = 32).
#define ISSUE_LOADS(XS, WS, CH) do {                                            \
    const int k0_ = kbase + (CH) * BK;                                          \
    _Pragma("unroll")                                                           \
    for (int t = 0; t < 4; ++t) {                                               \
      const int f_ = tid + t * 256;                                             \
      const int r_ = f_ >> 5, c4_ = f_ & 31;                                    \
      XS[t] = *reinterpret_cast<const f32x4*>(                                  \
          x + (size_t)r_ * D_DIM + k0_ + c4_ * 4);                              \
      WS[t] = *reinterpret_cast<const f32x4*>(                                  \
          wptr + (size_t)(erow0 + r_) * D_DIM + k0_ + c4_ * 4);                 \
    } } while (0)

// Convert staged fp32 -> bf16 and write swizzled LDS buffer BUF.
#define CVT_WRITE(XS, WS, BUF) do {                                             \
    _Pragma("unroll")                                                           \
    for (int t = 0; t < 4; ++t) {                                               \
      const int f_ = tid + t * 256;                                             \
      const int r_ = f_ >> 5, c4_ = f_ & 31;                                    \
      const int sc_ = (c4_ * 4) ^ ((r_ & 7) << 3);                              \
      s16x4 xv_, wv_;                                                           \
      _Pragma("unroll")                                                         \
      for (int j = 0; j < 4; ++j) {                                             \
        xv_[j] = (short)f2bf(XS[t][j]);                                         \
        wv_[j] = (short)f2bf(WS[t][j]);                                         \
      }                                                                         \
      *reinterpret_cast<s16x4*>(&lds[BUF][0][r_ * BK + sc_]) = xv_;             \
      *reinterpret_cast<s16x4*>(&lds[BUF][1][r_ * BK + sc_]) = wv_;             \
    } } while (0)

// 4 K-steps of 32: read A/B fragments (swizzled) and MFMA.
#define MFMA_STEP(BUF) do {                                                     \
    _Pragma("unroll")                                                           \
    for (int ks = 0; ks < 4; ++ks) {                                            \
      const int ce_ = ks * 32 + kg;                                             \
      s16x8 av_ = *reinterpret_cast<const s16x8*>(                              \
          &lds[BUF][0][arow * BK + (ce_ ^ axor)]);                              \
      s16x8 bv_ = *reinterpret_cast<const s16x8*>(                              \
          &lds[BUF][1][brow * BK + (ce_ ^ bxor)]);                              \
      acc = __builtin_amdgcn_mfma_f32_16x16x32_bf16(av_, bv_, acc, 0, 0, 0);    \
    } } while (0)

__global__ __launch_bounds__(256, 4) void qkv_gemm(
    const float* __restrict__ x, const float* __restrict__ wq,
    const float* __restrict__ wk, const float* __restrict__ wv,
    float* __restrict__ out)
{
  // [buf][0=x / 1=w][row * BK + col], bf16 as ushort.  2*2*32*128*2B = 32 KiB
  __shared__ unsigned short lds[2][2][BN * BK];

  const int bid    = blockIdx.x;
  const int tile   = bid >> 3;       // 0..319
  const int kslice = bid & 7;        // 0..7
  const int kbase  = kslice * KS;

  const int e0 = tile * BN;
  const float* wptr;
  int outbase, erow0;
  if (e0 < 8192)      { wptr = wq; outbase = 0;      erow0 = e0; }
  else if (e0 < 9216) { wptr = wk; outbase = 262144; erow0 = e0 - 8192; }
  else                { wptr = wv; outbase = 294912; erow0 = e0 - 9216; }

  const int tid  = threadIdx.x;
  const int lane = tid & 63;
  const int w    = tid >> 6;     // wave 0..3

  // MFMA fragment addressing (wave quadrant of the 32x32 tile)
  const int wm   = w >> 1, wn = w & 1;
  const int arow = wm * 16 + (lane & 15);   // batch row
  const int brow = wn * 16 + (lane & 15);   // weight row (within tile)
  const int kg   = (lane >> 4) * 8;         // k-group offset
  const int axor = (arow & 7) << 3;
  const int bxor = (brow & 7) << 3;

  f32x4 acc = {0.f, 0.f, 0.f, 0.f};
  f32x4 xs0[4], ws0[4], xs1[4], ws1[4];

  ISSUE_LOADS(xs0, ws0, 0);
  ISSUE_LOADS(xs1, ws1, 1);

  for (int c = 0; c < NCHUNK; c += 2) {
    CVT_WRITE(xs0, ws0, 0);
    if (c + 2 < NCHUNK) ISSUE_LOADS(xs0, ws0, c + 2);
    __syncthreads();
    MFMA_STEP(0);

    CVT_WRITE(xs1, ws1, 1);
    if (c + 3 < NCHUNK) ISSUE_LOADS(xs1, ws1, c + 3);
    __syncthreads();
    MFMA_STEP(1);
  }

  // Epilogue: C/D layout col = lane&15 (N / weight row), row = (lane>>4)*4+r (M / batch)
  const int nloc  = wn * 16 + (lane & 15);
  const int er    = erow0 + nloc;
  const int obase = outbase + (er >> 7) * (32 * 128) + (er & 127);
  const int mb0   = wm * 16 + (lane >> 4) * 4;
  #pragma unroll
  for (int r = 0; r < 4; ++r)
    atomicAdd(&out[obase + (size_t)(mb0 + r) * 128], acc[r]);
}

extern "C" void kernel_launch(void* const* d_in, const int* in_sizes, int n_in,
                              void* d_out, int out_size, void* d_ws, size_t ws_size,
                              hipStream_t stream) {
  const float* x  = (const float*)d_in[0];
  const float* wq = (const float*)d_in[1];
  const float* wk = (const float*)d_in[2];
  const float* wv = (const float*)d_in[3];
  float* out = (float*)d_out;
  hipMemsetAsync(out, 0, (size_t)out_size * sizeof(float), stream);
  qkv_gemm<<<dim3(320 * SPLITK), dim3(256), 0, stream>>>(x, wq, wk, wv, out);
}